// Round 7
// baseline (133.954 us; speedup 1.0000x reference)
//
#include <hip/hip_runtime.h>

// Path signature, depth 4: B=32, L=1024, d=8, fp32.
// Levels: S1(8) S2(64) S3(512) S4(4096); sig stride 4680 floats.
//
// R6 (resubmitted R7 after broker timeout): ONE fused kernel, 256 blocks x
// 256 threads (guaranteed co-resident: 4 waves/block on 4 SIMDs, >=1 block/CU
// capacity even at 256 VGPR), device-scope atomic grid barriers between phases:
//   Phase A: 1024 waves, one full-state 32-increment chunk sig each -> ws.
//   Phase B: 512 waves, k-sliced fold of 8 chunk sigs -> partial (dbuf prefetch).
//   Phase C: 128 waves, k-sliced fold of 4 partials -> d_out.
// Lessons: (R2) never unroll fold loops (VGPR-cap spill = 50MB scratch);
// (R3) waves need reg headroom beyond live state or loads serialize;
// (R5) serial fold depth dominates launch overhead (31-deep merged fold lost
// 13us to the 7+3 split) -> keep the shallow tree, fuse via grid barrier.

#define D 8
#define LPATH 1024
#define NINC 1023
#define BATCH 32
#define CHUNKS 32
#define MSTEP 32
#define SIG_STRIDE 4680
#define OFF2 8
#define OFF3 72
#define OFF4 584
#define NBLOCKS 256
#define FLAGS_BYTE_OFF (32u << 20)  // flags live 32 MiB into ws (sig data: 19.2 MB)

__device__ __forceinline__ float readlane_f(float v, int l) {
  return __builtin_bit_cast(float, __builtin_amdgcn_readlane(__builtin_bit_cast(int, v), l));
}

__device__ __forceinline__ void load8(const float* __restrict__ p, float* dst) {
  float4 lo = *(const float4*)p;
  float4 hi = *(const float4*)(p + 4);
  dst[0] = lo.x; dst[1] = lo.y; dst[2] = lo.z; dst[3] = lo.w;
  dst[4] = hi.x; dst[5] = hi.y; dst[6] = hi.z; dst[7] = hi.w;
}

__device__ __forceinline__ void store8(float* __restrict__ p, const float* src) {
  *(float4*)p       = make_float4(src[0], src[1], src[2], src[3]);
  *(float4*)(p + 4) = make_float4(src[4], src[5], src[6], src[7]);
}

// Grid-wide barrier. All 256 blocks are co-resident by construction.
// RELEASE add publishes prior plain stores to agent scope (L2 writeback);
// final ACQUIRE load invalidates stale lines before consuming remote data.
__device__ __forceinline__ void grid_barrier(unsigned int* flag) {
  __syncthreads();
  if (threadIdx.x == 0) {
    __hip_atomic_fetch_add(flag, 1u, __ATOMIC_RELEASE, __HIP_MEMORY_SCOPE_AGENT);
    while (__hip_atomic_load(flag, __ATOMIC_RELAXED, __HIP_MEMORY_SCOPE_AGENT) <
           (unsigned int)NBLOCKS) {
      __builtin_amdgcn_s_sleep(8);
    }
    (void)__hip_atomic_load(flag, __ATOMIC_ACQUIRE, __HIP_MEMORY_SCOPE_AGENT);
  }
  __syncthreads();
}

// ---- k-sliced fold machinery (phases B/C). Wave q owns S4[.][.][2q,2q+1][.]
// plus replicated S1,S2,S3 (identical arithmetic in all 4 q-waves).
struct BSlice {
  float b1j, b2own;
  float b2row[D], b3own[D];
  float b2k[2][D], b3k[2][D], b4[2][D];
};

__device__ __forceinline__ void load_B(const float* __restrict__ Bp, BSlice& B,
                                       int j, int lane, int k0) {
  B.b1j = Bp[j];
  B.b2own = Bp[OFF2 + lane];
  load8(Bp + OFF2 + j * 8, B.b2row);
  load8(Bp + OFF3 + lane * 8, B.b3own);
#pragma unroll
  for (int t = 0; t < 2; ++t) {
    load8(Bp + OFF2 + (k0 + t) * 8, B.b2k[t]);
    load8(Bp + OFF3 + (j * 8 + k0 + t) * 8, B.b3k[t]);
    load8(Bp + OFF4 + lane * 64 + (k0 + t) * 8, B.b4[t]);
  }
}

__device__ __forceinline__ void fold_B(float& s1, float& s2, float s3[D],
                                       float s4[2][D], const BSlice& B, int i,
                                       int k0) {
  float b1i = __shfl(B.b1j, i, 64);
  float sb1[D];
#pragma unroll
  for (int m = 0; m < D; ++m) sb1[m] = readlane_f(B.b1j, m);

#pragma unroll
  for (int t = 0; t < 2; ++t) {
    float a3k = s3[k0 + t];
#pragma unroll
    for (int m = 0; m < D; ++m) {
      float v = __builtin_fmaf(a3k, sb1[m], s4[t][m] + B.b4[t][m]);
      v = __builtin_fmaf(s2, B.b2k[t][m], v);
      s4[t][m] = __builtin_fmaf(s1, B.b3k[t][m], v);
    }
  }
#pragma unroll
  for (int k = 0; k < D; ++k) {
    float v = __builtin_fmaf(s1, B.b2row[k], s3[k] + B.b3own[k]);
    s3[k] = __builtin_fmaf(s2, sb1[k], v);
  }
  s2 = s2 + B.b2own + s1 * B.b1j;
  s1 = s1 + b1i;
}

// Fold sigs at base + n*step*SIG_STRIDE, n=1..count (count odd), into state.
// 2-deep register double buffer so the next B-load latency overlaps fold VALU.
__device__ __forceinline__ void fold_seq(const float* __restrict__ base, int step,
                                         int count, float& s1, float& s2,
                                         float s3[D], float s4[2][D], int i,
                                         int j, int lane, int k0) {
  BSlice buf0, buf1;
  load_B(base + (size_t)step * SIG_STRIDE, buf0, j, lane, k0);
#pragma unroll 1
  for (int n = 1; n + 2 <= count; n += 2) {
    load_B(base + (size_t)(n + 1) * step * SIG_STRIDE, buf1, j, lane, k0);
    fold_B(s1, s2, s3, s4, buf0, i, k0);
    load_B(base + (size_t)(n + 2) * step * SIG_STRIDE, buf0, j, lane, k0);
    fold_B(s1, s2, s3, s4, buf1, i, k0);
  }
  fold_B(s1, s2, s3, s4, buf0, i, k0);  // last (count odd)
}

__global__ __launch_bounds__(256, 1) void sig_fused(const float* __restrict__ path,
                                                    float* __restrict__ ws,
                                                    float* __restrict__ out,
                                                    unsigned int* __restrict__ flags) {
  const int wv   = threadIdx.x >> 6;  // wave in block, 0..3
  const int lane = threadIdx.x & 63;
  const int gw   = blockIdx.x * 4 + wv;  // 0..1023
  const int i = lane >> 3;
  const int j = lane & 7;

  // ---------------- Phase A: full-state chunk signature, 1 wave/chunk -------
  {
    const int b = gw >> 5;
    const int c = gw & (CHUNKS - 1);
    const float* __restrict__ pj = path + (size_t)b * (LPATH * D) + j;
    const int g0 = c * MSTEP;

    float pc = pj[g0 * D];
    int nx = g0 + 1; nx = nx > NINC ? NINC : nx;
    float pnext = pj[nx * D];

    float s1 = 0.f, s2 = 0.f;
    float s3[D] = {0.f, 0.f, 0.f, 0.f, 0.f, 0.f, 0.f, 0.f};
    float s4[D][D];
#pragma unroll
    for (int k = 0; k < D; ++k)
#pragma unroll
      for (int m = 0; m < D; ++m) s4[k][m] = 0.f;

#pragma unroll 1
    for (int t = 0; t < MSTEP; ++t) {
      float pn = pnext;
      int n2 = g0 + t + 2; n2 = n2 > NINC ? NINC : n2;  // clamp -> zero-inc pad
      pnext = pj[n2 * D];

      float wj = pn - pc;
      pc = pn;
      float wi = __shfl(wj, i, 64);
      float wm[D];
#pragma unroll
      for (int m = 0; m < D; ++m) wm[m] = readlane_f(wj, m);

      // level 4: S4 += S3(x)w + S2(x)w^2/2 + S1(x)w^3/6 + w^4/24 (Horner)
      float h1  = __builtin_fmaf(wi, 0.25f, s1);
      float h2  = __builtin_fmaf(h1, wj * (1.f / 3.f), s2);
      float hb2 = h2 * 0.5f;
      float b3[D];
#pragma unroll
      for (int k = 0; k < D; ++k) b3[k] = __builtin_fmaf(hb2, wm[k], s3[k]);
#pragma unroll
      for (int k = 0; k < D; ++k)
#pragma unroll
        for (int m = 0; m < D; ++m)
          s4[k][m] = __builtin_fmaf(b3[k], wm[m], s4[k][m]);

      // level 3
      float c1 = __builtin_fmaf(wi, (1.f / 3.f), s1);
      float c2 = __builtin_fmaf(c1, wj * 0.5f, s2);
#pragma unroll
      for (int k = 0; k < D; ++k) s3[k] = __builtin_fmaf(c2, wm[k], s3[k]);

      // levels 2, 1
      float d1 = __builtin_fmaf(wi, 0.5f, s1);
      s2 = __builtin_fmaf(d1, wj, s2);
      s1 += wi;
    }

    float* __restrict__ slot = ws + (size_t)(b * CHUNKS + c) * SIG_STRIDE;
    if (j == 0) slot[i] = s1;
    slot[OFF2 + lane] = s2;
    store8(slot + OFF3 + lane * 8, s3);
#pragma unroll
    for (int k = 0; k < D; ++k) store8(slot + OFF4 + lane * 64 + k * 8, s4[k]);
  }

  grid_barrier(&flags[0]);

  // ---------------- Phase B: fold 8 chunk sigs (k-sliced, 512 waves) --------
  if (gw < 512) {
    const int q = gw & 3;
    const int g = (gw >> 2) & 3;
    const int b = gw >> 4;
    const int k0 = q * 2;
    float* __restrict__ base = ws + (size_t)(b * CHUNKS + g * 8) * SIG_STRIDE;

    float s1 = base[i];
    float s2 = base[OFF2 + lane];
    float s3[D], s4[2][D];
    load8(base + OFF3 + lane * 8, s3);
    load8(base + OFF4 + lane * 64 + k0 * 8, s4[0]);
    load8(base + OFF4 + lane * 64 + (k0 + 1) * 8, s4[1]);

    fold_seq(base, 1, 7, s1, s2, s3, s4, i, j, lane, k0);

    store8(base + OFF4 + lane * 64 + k0 * 8, s4[0]);
    store8(base + OFF4 + lane * 64 + (k0 + 1) * 8, s4[1]);
    if (q == 0) {
      if (j == 0) base[i] = s1;
      base[OFF2 + lane] = s2;
      store8(base + OFF3 + lane * 8, s3);
    }
  }

  grid_barrier(&flags[1]);

  // ---------------- Phase C: fold the 4 partials, write d_out ---------------
  if (gw < 128) {
    const int q = gw & 3;
    const int b = gw >> 2;
    const int k0 = q * 2;
    const float* __restrict__ base = ws + (size_t)b * CHUNKS * SIG_STRIDE;

    float s1 = base[i];
    float s2 = base[OFF2 + lane];
    float s3[D], s4[2][D];
    load8(base + OFF3 + lane * 8, s3);
    load8(base + OFF4 + lane * 64 + k0 * 8, s4[0]);
    load8(base + OFF4 + lane * 64 + (k0 + 1) * 8, s4[1]);

    fold_seq(base, 8, 3, s1, s2, s3, s4, i, j, lane, k0);

    // d_out: S1 (32x8) | S2 (32x64) | S3 (32x512) | S4 (32x4096)
    if (q == 0) {
      if (j == 0) out[b * 8 + i] = s1;
      out[256 + b * 64 + lane] = s2;
      store8(out + 2304 + b * 512 + lane * 8, s3);
    }
    store8(out + 18688 + b * 4096 + lane * 64 + k0 * 8, s4[0]);
    store8(out + 18688 + b * 4096 + lane * 64 + (k0 + 1) * 8, s4[1]);
  }
}

extern "C" void kernel_launch(void* const* d_in, const int* in_sizes, int n_in,
                              void* d_out, int out_size, void* d_ws, size_t ws_size,
                              hipStream_t stream) {
  const float* path = (const float*)d_in[0];
  // d_in[1] = depth (==4), compile-time specialized.
  float* out = (float*)d_out;
  float* ws  = (float*)d_ws;  // sig data: first 19.2 MB; flags at +32 MiB
  unsigned int* flags = (unsigned int*)((char*)d_ws + FLAGS_BYTE_OFF);

  // zero the two grid-barrier counters (capture-legal async memset)
  hipMemsetAsync(flags, 0, 2 * sizeof(unsigned int), stream);
  sig_fused<<<dim3(NBLOCKS), dim3(256), 0, stream>>>(path, ws, out, flags);
}